// Round 1
// baseline (1479.861 us; speedup 1.0000x reference)
//
#include <hip/hip_runtime.h>

// TriangleMultiplication (outgoing, ENDING=false), B=1, N=512, D=128, fp32.
//   x_norm = LN(x); h = (x_norm @ p_in^T) * sigmoid(x_norm @ g_in^T)
//   a = h[:,:128] ; b = h[:,128:]
//   t[i,j,d] = sum_k a[i,k,d]*b[j,k,d]
//   out = LN(t) @ p_out^T * sigmoid(x_norm @ g_out^T)
//
// ws layout (fp32): a_t[128][262144], b_t[128][262144], t_t[128][262144]
//   (d-major planes so the einsum is 128 clean 512^3 GEMMs)  -> 384 MB total.

#define NROW 512
#define MTOT (512 * 512)
#define DD 128

__device__ __forceinline__ float sigm(float v) {
    return 1.0f / (1.0f + __expf(-v));
}

// ---------------------------------------------------------------------------
// Stage 1: LayerNorm(x) + dual GEMM (proj & gate) -> a_t, b_t (d-major planes)
// grid 4096 blocks x 256 threads; each block owns 64 rows of the 262144.
// ---------------------------------------------------------------------------
__global__ __launch_bounds__(256, 2) void tm_stage1(
    const float* __restrict__ x,
    const float* __restrict__ nin_w, const float* __restrict__ nin_b,
    const float* __restrict__ p_in_w, const float* __restrict__ g_in_w,
    float* __restrict__ a_t, float* __restrict__ b_t)
{
    __shared__ float Xs[128][64];   // xn tile, k-major: Xs[k][r_local]
    __shared__ float Ws[128][64];   // weight chunk, k-major: Ws[k][c_local]
    __shared__ float w_s[128], b_s[128];

    const int tid = threadIdx.x;
    const int row = tid >> 2;      // 0..63
    const int q   = tid & 3;       // 0..3 (quarter of a 128-row)
    const int tx  = tid & 15;      // GEMM col group
    const int ty  = tid >> 4;      // GEMM row group
    const int r0  = blockIdx.x * 64;

    if (tid < 128) { w_s[tid] = nin_w[tid]; b_s[tid] = nin_b[tid]; }

    // ---- Phase A: load 64 x-rows, LayerNorm, write k-major tile
    {
        const float* src = x + (size_t)(r0 + row) * DD + q * 32;
        float v[32];
        float s = 0.f, ss = 0.f;
#pragma unroll
        for (int it = 0; it < 8; ++it) {
            float4 f = *(const float4*)(src + it * 4);
            v[it*4+0] = f.x; v[it*4+1] = f.y; v[it*4+2] = f.z; v[it*4+3] = f.w;
            s  += f.x + f.y + f.z + f.w;
            ss += f.x*f.x + f.y*f.y + f.z*f.z + f.w*f.w;
        }
        // 4 lanes per row are consecutive -> butterfly within the wave
        s  += __shfl_xor(s, 1);  s  += __shfl_xor(s, 2);
        ss += __shfl_xor(ss, 1); ss += __shfl_xor(ss, 2);
        float mu   = s * (1.0f / 128.0f);
        float var  = ss * (1.0f / 128.0f) - mu * mu;
        float rstd = rsqrtf(var + 1e-5f);
        __syncthreads();           // w_s/b_s ready
#pragma unroll
        for (int j = 0; j < 32; ++j) {
            int k = q * 32 + j;
            Xs[k][row] = (v[j] - mu) * rstd * w_s[k] + b_s[k];
        }
    }

    // ---- Phase B: 4 chunk-pairs of 64 columns (proj then gate), h = p*sig(g)
    for (int cp = 0; cp < 4; ++cp) {
        __syncthreads();   // previous chunk's Ws readers done / Xs visible
        {
            const float* srcw = p_in_w + (size_t)(cp * 64 + row) * DD + q * 32;
#pragma unroll
            for (int it = 0; it < 8; ++it) {
                float4 f = *(const float4*)(srcw + it * 4);
                int k = q * 32 + it * 4;
                Ws[k+0][row] = f.x; Ws[k+1][row] = f.y;
                Ws[k+2][row] = f.z; Ws[k+3][row] = f.w;
            }
        }
        __syncthreads();
        float accp[4][4] = {};
#pragma unroll 4
        for (int k = 0; k < 128; ++k) {
            float4 a4 = *(const float4*)&Xs[k][ty * 4];
            float4 w4 = *(const float4*)&Ws[k][tx * 4];
            float av[4] = {a4.x, a4.y, a4.z, a4.w};
            float wv[4] = {w4.x, w4.y, w4.z, w4.w};
#pragma unroll
            for (int ri = 0; ri < 4; ++ri)
#pragma unroll
                for (int ci = 0; ci < 4; ++ci)
                    accp[ri][ci] = fmaf(av[ri], wv[ci], accp[ri][ci]);
        }
        __syncthreads();
        {
            const float* srcw = g_in_w + (size_t)(cp * 64 + row) * DD + q * 32;
#pragma unroll
            for (int it = 0; it < 8; ++it) {
                float4 f = *(const float4*)(srcw + it * 4);
                int k = q * 32 + it * 4;
                Ws[k+0][row] = f.x; Ws[k+1][row] = f.y;
                Ws[k+2][row] = f.z; Ws[k+3][row] = f.w;
            }
        }
        __syncthreads();
        float accg[4][4] = {};
#pragma unroll 4
        for (int k = 0; k < 128; ++k) {
            float4 a4 = *(const float4*)&Xs[k][ty * 4];
            float4 w4 = *(const float4*)&Ws[k][tx * 4];
            float av[4] = {a4.x, a4.y, a4.z, a4.w};
            float wv[4] = {w4.x, w4.y, w4.z, w4.w};
#pragma unroll
            for (int ri = 0; ri < 4; ++ri)
#pragma unroll
                for (int ci = 0; ci < 4; ++ci)
                    accg[ri][ci] = fmaf(av[ri], wv[ci], accg[ri][ci]);
        }
        // h = proj * sigmoid(gate); scatter to d-major planes (64B-coalesced)
#pragma unroll
        for (int ci = 0; ci < 4; ++ci) {
            int c = cp * 64 + tx * 4 + ci;
            float4 hv;
            hv.x = accp[0][ci] * sigm(accg[0][ci]);
            hv.y = accp[1][ci] * sigm(accg[1][ci]);
            hv.z = accp[2][ci] * sigm(accg[2][ci]);
            hv.w = accp[3][ci] * sigm(accg[3][ci]);
            float* dst = (c < DD) ? (a_t + (size_t)c * MTOT)
                                  : (b_t + (size_t)(c - DD) * MTOT);
            *(float4*)(dst + r0 + ty * 4) = hv;
        }
    }
}

// ---------------------------------------------------------------------------
// Stage 2: t_t[d] = A_d * B_d^T  (128 batched 512x512x512 fp32 GEMMs)
// grid (8 j-tiles, 8 i-tiles, 128 d) x 256 threads, 64x64 tile, BK=32.
// ---------------------------------------------------------------------------
__global__ __launch_bounds__(256, 2) void tm_einsum(
    const float* __restrict__ a_t, const float* __restrict__ b_t,
    float* __restrict__ t_t)
{
    __shared__ float As[32][64];   // k-major: As[kk][i_local]
    __shared__ float Bs[32][64];
    const int tid = threadIdx.x;
    const int il  = tid >> 2;
    const int q   = tid & 3;
    const int tx  = tid & 15;
    const int ty  = tid >> 4;
    const int j0  = blockIdx.x * 64;
    const int i0  = blockIdx.y * 64;
    const int d   = blockIdx.z;

    const float* ap = a_t + (size_t)d * MTOT + (size_t)(i0 + il) * NROW;
    const float* bp = b_t + (size_t)d * MTOT + (size_t)(j0 + il) * NROW;

    float acc[4][4] = {};
    for (int kc = 0; kc < 16; ++kc) {
        const int kb = kc * 32 + q * 8;
        __syncthreads();
        {
            float4 f0 = *(const float4*)(ap + kb);
            float4 f1 = *(const float4*)(ap + kb + 4);
            int ks = q * 8;
            As[ks+0][il] = f0.x; As[ks+1][il] = f0.y;
            As[ks+2][il] = f0.z; As[ks+3][il] = f0.w;
            As[ks+4][il] = f1.x; As[ks+5][il] = f1.y;
            As[ks+6][il] = f1.z; As[ks+7][il] = f1.w;
            float4 g0 = *(const float4*)(bp + kb);
            float4 g1 = *(const float4*)(bp + kb + 4);
            Bs[ks+0][il] = g0.x; Bs[ks+1][il] = g0.y;
            Bs[ks+2][il] = g0.z; Bs[ks+3][il] = g0.w;
            Bs[ks+4][il] = g1.x; Bs[ks+5][il] = g1.y;
            Bs[ks+6][il] = g1.z; Bs[ks+7][il] = g1.w;
        }
        __syncthreads();
#pragma unroll
        for (int kk = 0; kk < 32; ++kk) {
            float4 a4 = *(const float4*)&As[kk][ty * 4];
            float4 b4 = *(const float4*)&Bs[kk][tx * 4];
            float av[4] = {a4.x, a4.y, a4.z, a4.w};
            float bv[4] = {b4.x, b4.y, b4.z, b4.w};
#pragma unroll
            for (int ri = 0; ri < 4; ++ri)
#pragma unroll
                for (int ci = 0; ci < 4; ++ci)
                    acc[ri][ci] = fmaf(av[ri], bv[ci], acc[ri][ci]);
        }
    }
    float* dst = t_t + (size_t)d * MTOT + (size_t)(i0 + ty * 4) * NROW + j0 + tx * 4;
#pragma unroll
    for (int ri = 0; ri < 4; ++ri) {
        float4 o = {acc[ri][0], acc[ri][1], acc[ri][2], acc[ri][3]};
        *(float4*)(dst + (size_t)ri * NROW) = o;
    }
}

// ---------------------------------------------------------------------------
// Stage 3: recompute go = sigmoid(LN(x) @ g_out^T) in registers, then
// LN(t) @ p_out^T * go -> out.  grid 4096 x 256, 64 rows/block.
// ---------------------------------------------------------------------------
__global__ __launch_bounds__(256, 2) void tm_stage3(
    const float* __restrict__ x,
    const float* __restrict__ nin_w, const float* __restrict__ nin_b,
    const float* __restrict__ g_out_w,
    const float* __restrict__ t_t,
    const float* __restrict__ non_w, const float* __restrict__ non_b,
    const float* __restrict__ p_out_w,
    float* __restrict__ out)
{
    __shared__ float Ts[64][129];   // r-major tile (xn first, then t), +1 pad
    __shared__ float Ws[128][64];   // weight chunk, k-major
    __shared__ float w_s[128], b_s[128];

    const int tid = threadIdx.x;
    const int row = tid >> 2;
    const int q   = tid & 3;
    const int tx  = tid & 15;
    const int ty  = tid >> 4;
    const int r0  = blockIdx.x * 64;

    if (tid < 128) { w_s[tid] = nin_w[tid]; b_s[tid] = nin_b[tid]; }

    // ---- Phase A': LN(x rows) -> Ts[row][k]
    {
        const float* src = x + (size_t)(r0 + row) * DD + q * 32;
        float v[32];
        float s = 0.f, ss = 0.f;
#pragma unroll
        for (int it = 0; it < 8; ++it) {
            float4 f = *(const float4*)(src + it * 4);
            v[it*4+0] = f.x; v[it*4+1] = f.y; v[it*4+2] = f.z; v[it*4+3] = f.w;
            s  += f.x + f.y + f.z + f.w;
            ss += f.x*f.x + f.y*f.y + f.z*f.z + f.w*f.w;
        }
        s  += __shfl_xor(s, 1);  s  += __shfl_xor(s, 2);
        ss += __shfl_xor(ss, 1); ss += __shfl_xor(ss, 2);
        float mu   = s * (1.0f / 128.0f);
        float var  = ss * (1.0f / 128.0f) - mu * mu;
        float rstd = rsqrtf(var + 1e-5f);
        __syncthreads();
#pragma unroll
        for (int j = 0; j < 32; ++j) {
            int jj = (j + q * 8) & 31;          // bank stagger
            int k  = q * 32 + jj;
            Ts[row][k] = (v[jj] - mu) * rstd * w_s[k] + b_s[k];
        }
    }

    // ---- go = sigmoid(xn @ g_out^T), kept in registers (matching tile map)
    float gov[2][4][4];
    for (int cp = 0; cp < 2; ++cp) {
        __syncthreads();
        {
            const float* srcw = g_out_w + (size_t)(cp * 64 + row) * DD + q * 32;
#pragma unroll
            for (int it = 0; it < 8; ++it) {
                float4 f = *(const float4*)(srcw + it * 4);
                int k = q * 32 + it * 4;
                Ws[k+0][row] = f.x; Ws[k+1][row] = f.y;
                Ws[k+2][row] = f.z; Ws[k+3][row] = f.w;
            }
        }
        __syncthreads();
        float acc[4][4] = {};
#pragma unroll 4
        for (int k = 0; k < 128; ++k) {
            float4 w4 = *(const float4*)&Ws[k][tx * 4];
            float wv[4] = {w4.x, w4.y, w4.z, w4.w};
            float av[4];
#pragma unroll
            for (int ri = 0; ri < 4; ++ri) av[ri] = Ts[ty * 4 + ri][k];
#pragma unroll
            for (int ri = 0; ri < 4; ++ri)
#pragma unroll
                for (int ci = 0; ci < 4; ++ci)
                    acc[ri][ci] = fmaf(av[ri], wv[ci], acc[ri][ci]);
        }
#pragma unroll
        for (int ri = 0; ri < 4; ++ri)
#pragma unroll
            for (int ci = 0; ci < 4; ++ci)
                gov[cp][ri][ci] = sigm(acc[ri][ci]);
    }

    // ---- Phase B: load t tile (d-major planes -> r-major LDS), LayerNorm
    __syncthreads();                       // xn readers done
    if (tid < 128) { w_s[tid] = non_w[tid]; b_s[tid] = non_b[tid]; }
    {
        const int rl = tid & 63;
        const int dg = tid >> 6;
        for (int it = 0; it < 32; ++it) {
            int dcur = it * 4 + dg;
            Ts[rl][dcur] = t_t[(size_t)dcur * MTOT + r0 + rl];
        }
    }
    __syncthreads();
    {
        float v2[32];
        float s = 0.f, ss = 0.f;
#pragma unroll
        for (int j = 0; j < 32; ++j) {
            int jj = (j + q * 8) & 31;
            float val = Ts[row][q * 32 + jj];
            v2[j] = val;
            s += val; ss += val * val;
        }
        s  += __shfl_xor(s, 1);  s  += __shfl_xor(s, 2);
        ss += __shfl_xor(ss, 1); ss += __shfl_xor(ss, 2);
        float mu   = s * (1.0f / 128.0f);
        float var  = ss * (1.0f / 128.0f) - mu * mu;
        float rstd = rsqrtf(var + 1e-5f);
#pragma unroll
        for (int j = 0; j < 32; ++j) {
            int jj = (j + q * 8) & 31;
            int k  = q * 32 + jj;
            Ts[row][k] = (v2[j] - mu) * rstd * w_s[k] + b_s[k];
        }
    }

    // ---- Phase C: out = (t_norm @ p_out^T) * go
    for (int cp = 0; cp < 2; ++cp) {
        __syncthreads();
        {
            const float* srcw = p_out_w + (size_t)(cp * 64 + row) * DD + q * 32;
#pragma unroll
            for (int it = 0; it < 8; ++it) {
                float4 f = *(const float4*)(srcw + it * 4);
                int k = q * 32 + it * 4;
                Ws[k+0][row] = f.x; Ws[k+1][row] = f.y;
                Ws[k+2][row] = f.z; Ws[k+3][row] = f.w;
            }
        }
        __syncthreads();
        float acc[4][4] = {};
#pragma unroll 4
        for (int k = 0; k < 128; ++k) {
            float4 w4 = *(const float4*)&Ws[k][tx * 4];
            float wv[4] = {w4.x, w4.y, w4.z, w4.w};
            float av[4];
#pragma unroll
            for (int ri = 0; ri < 4; ++ri) av[ri] = Ts[ty * 4 + ri][k];
#pragma unroll
            for (int ri = 0; ri < 4; ++ri)
#pragma unroll
                for (int ci = 0; ci < 4; ++ci)
                    acc[ri][ci] = fmaf(av[ri], wv[ci], acc[ri][ci]);
        }
#pragma unroll
        for (int ri = 0; ri < 4; ++ri) {
            size_t r = (size_t)(r0 + ty * 4 + ri);
            float4 o;
            o.x = acc[ri][0] * gov[cp][ri][0];
            o.y = acc[ri][1] * gov[cp][ri][1];
            o.z = acc[ri][2] * gov[cp][ri][2];
            o.w = acc[ri][3] * gov[cp][ri][3];
            *(float4*)(out + r * DD + cp * 64 + tx * 4) = o;
        }
    }
}

// ---------------------------------------------------------------------------
extern "C" void kernel_launch(void* const* d_in, const int* in_sizes, int n_in,
                              void* d_out, int out_size, void* d_ws, size_t ws_size,
                              hipStream_t stream)
{
    const float* x       = (const float*)d_in[0];
    const float* nin_w   = (const float*)d_in[1];
    const float* nin_b   = (const float*)d_in[2];
    const float* p_in_w  = (const float*)d_in[3];
    const float* g_in_w  = (const float*)d_in[4];
    const float* non_w   = (const float*)d_in[5];
    const float* non_b   = (const float*)d_in[6];
    const float* p_out_w = (const float*)d_in[7];
    const float* g_out_w = (const float*)d_in[8];
    float* out = (float*)d_out;

    float* a_t = (float*)d_ws;                       // [128][262144]
    float* b_t = a_t + (size_t)DD * MTOT;            // [128][262144]
    float* t_t = b_t + (size_t)DD * MTOT;            // [128][262144]

    tm_stage1<<<dim3(4096), dim3(256), 0, stream>>>(
        x, nin_w, nin_b, p_in_w, g_in_w, a_t, b_t);
    tm_einsum<<<dim3(8, 8, 128), dim3(256), 0, stream>>>(a_t, b_t, t_t);
    tm_stage3<<<dim3(4096), dim3(256), 0, stream>>>(
        x, nin_w, nin_b, g_out_w, t_t, non_w, non_b, p_out_w, out);
}

// Round 3
// 1166.840 us; speedup vs baseline: 1.2683x; 1.2683x over previous
//
#include <hip/hip_runtime.h>

// TriangleMultiplication (outgoing, ENDING=false), B=1, N=512, D=128, fp32.
//   x_norm = LN(x); h = (x_norm @ p_in^T) * sigmoid(x_norm @ g_in^T)
//   a = h[:,:128] ; b = h[:,128:]
//   t[i,j,d] = sum_k a[i,k,d]*b[j,k,d]
//   out = LN(t) @ p_out^T * sigmoid(x_norm @ g_out^T)
//
// ws layout: a_hi/a_lo/b_hi/b_lo bf16 planes [128][262144] (split-bf16 of a,b)
//            + t_t fp32 [128][262144]  -> 402 MB total.
// Einsum runs as 128 batched 512^3 GEMMs in split-bf16 MFMA (3 mfma/product
// pair: hi*hi + hi*lo + lo*hi, rel err ~2^-16 -> fp32-equivalent here).

#define NROW 512
#define MTOT (512 * 512)
#define DD 128

typedef __bf16 bf16x8 __attribute__((ext_vector_type(8)));
typedef float f32x4 __attribute__((ext_vector_type(4)));

__device__ __forceinline__ float sigm(float v) {
    return 1.0f / (1.0f + __expf(-v));
}

// fp32 -> bf16 (RNE) via bit ops (avoids header API differences)
__device__ __forceinline__ unsigned short f2bf(float f) {
    unsigned int u = __float_as_uint(f);
    unsigned int r = (u + 0x7fffu + ((u >> 16) & 1u)) >> 16;
    return (unsigned short)r;
}
__device__ __forceinline__ float bf2f(unsigned short h) {
    return __uint_as_float(((unsigned int)h) << 16);
}

__device__ __forceinline__ void gl_lds16(const void* g, void* l) {
    __builtin_amdgcn_global_load_lds(
        (const __attribute__((address_space(1))) void*)g,
        (__attribute__((address_space(3))) void*)l, 16, 0, 0);
}

// ---------------------------------------------------------------------------
// Stage 1: LayerNorm(x) + dual GEMM (proj & gate) -> split-bf16 d-major planes
// grid 4096 blocks x 256 threads; each block owns 64 rows of the 262144.
// ---------------------------------------------------------------------------
__global__ __launch_bounds__(256, 2) void tm_stage1(
    const float* __restrict__ x,
    const float* __restrict__ nin_w, const float* __restrict__ nin_b,
    const float* __restrict__ p_in_w, const float* __restrict__ g_in_w,
    unsigned short* __restrict__ a_hi, unsigned short* __restrict__ a_lo,
    unsigned short* __restrict__ b_hi, unsigned short* __restrict__ b_lo)
{
    __shared__ float Xs[128][64];   // xn tile, k-major: Xs[k][r_local]
    __shared__ float Ws[128][64];   // weight chunk, k-major: Ws[k][c_local]
    __shared__ float w_s[128], b_s[128];

    const int tid = threadIdx.x;
    const int row = tid >> 2;      // 0..63
    const int q   = tid & 3;       // 0..3 (quarter of a 128-row)
    const int tx  = tid & 15;      // GEMM col group
    const int ty  = tid >> 4;      // GEMM row group
    const int r0  = blockIdx.x * 64;

    if (tid < 128) { w_s[tid] = nin_w[tid]; b_s[tid] = nin_b[tid]; }

    // ---- Phase A: load 64 x-rows, LayerNorm, write k-major tile
    {
        const float* src = x + (size_t)(r0 + row) * DD + q * 32;
        float v[32];
        float s = 0.f, ss = 0.f;
#pragma unroll
        for (int it = 0; it < 8; ++it) {
            float4 f = *(const float4*)(src + it * 4);
            v[it*4+0] = f.x; v[it*4+1] = f.y; v[it*4+2] = f.z; v[it*4+3] = f.w;
            s  += f.x + f.y + f.z + f.w;
            ss += f.x*f.x + f.y*f.y + f.z*f.z + f.w*f.w;
        }
        s  += __shfl_xor(s, 1);  s  += __shfl_xor(s, 2);
        ss += __shfl_xor(ss, 1); ss += __shfl_xor(ss, 2);
        float mu   = s * (1.0f / 128.0f);
        float var  = ss * (1.0f / 128.0f) - mu * mu;
        float rstd = rsqrtf(var + 1e-5f);
        __syncthreads();           // w_s/b_s ready
#pragma unroll
        for (int j = 0; j < 32; ++j) {
            int k = q * 32 + j;
            Xs[k][row] = (v[j] - mu) * rstd * w_s[k] + b_s[k];
        }
    }

    // ---- Phase B: 4 chunk-pairs of 64 columns (proj then gate), h = p*sig(g)
    for (int cp = 0; cp < 4; ++cp) {
        __syncthreads();
        {
            const float* srcw = p_in_w + (size_t)(cp * 64 + row) * DD + q * 32;
#pragma unroll
            for (int it = 0; it < 8; ++it) {
                float4 f = *(const float4*)(srcw + it * 4);
                int k = q * 32 + it * 4;
                Ws[k+0][row] = f.x; Ws[k+1][row] = f.y;
                Ws[k+2][row] = f.z; Ws[k+3][row] = f.w;
            }
        }
        __syncthreads();
        float accp[4][4] = {};
#pragma unroll 4
        for (int k = 0; k < 128; ++k) {
            float4 a4 = *(const float4*)&Xs[k][ty * 4];
            float4 w4 = *(const float4*)&Ws[k][tx * 4];
            float av[4] = {a4.x, a4.y, a4.z, a4.w};
            float wv[4] = {w4.x, w4.y, w4.z, w4.w};
#pragma unroll
            for (int ri = 0; ri < 4; ++ri)
#pragma unroll
                for (int ci = 0; ci < 4; ++ci)
                    accp[ri][ci] = fmaf(av[ri], wv[ci], accp[ri][ci]);
        }
        __syncthreads();
        {
            const float* srcw = g_in_w + (size_t)(cp * 64 + row) * DD + q * 32;
#pragma unroll
            for (int it = 0; it < 8; ++it) {
                float4 f = *(const float4*)(srcw + it * 4);
                int k = q * 32 + it * 4;
                Ws[k+0][row] = f.x; Ws[k+1][row] = f.y;
                Ws[k+2][row] = f.z; Ws[k+3][row] = f.w;
            }
        }
        __syncthreads();
        float accg[4][4] = {};
#pragma unroll 4
        for (int k = 0; k < 128; ++k) {
            float4 a4 = *(const float4*)&Xs[k][ty * 4];
            float4 w4 = *(const float4*)&Ws[k][tx * 4];
            float av[4] = {a4.x, a4.y, a4.z, a4.w};
            float wv[4] = {w4.x, w4.y, w4.z, w4.w};
#pragma unroll
            for (int ri = 0; ri < 4; ++ri)
#pragma unroll
                for (int ci = 0; ci < 4; ++ci)
                    accg[ri][ci] = fmaf(av[ri], wv[ci], accg[ri][ci]);
        }
        // h = proj * sigmoid(gate); split to bf16 hi/lo, scatter to planes
#pragma unroll
        for (int ci = 0; ci < 4; ++ci) {
            int c = cp * 64 + tx * 4 + ci;
            float hv[4];
            hv[0] = accp[0][ci] * sigm(accg[0][ci]);
            hv[1] = accp[1][ci] * sigm(accg[1][ci]);
            hv[2] = accp[2][ci] * sigm(accg[2][ci]);
            hv[3] = accp[3][ci] * sigm(accg[3][ci]);
            ushort4 h4, l4;
            {
                unsigned short h;
                h = f2bf(hv[0]); h4.x = h; l4.x = f2bf(hv[0] - bf2f(h));
                h = f2bf(hv[1]); h4.y = h; l4.y = f2bf(hv[1] - bf2f(h));
                h = f2bf(hv[2]); h4.z = h; l4.z = f2bf(hv[2] - bf2f(h));
                h = f2bf(hv[3]); h4.w = h; l4.w = f2bf(hv[3] - bf2f(h));
            }
            unsigned short* dh;
            unsigned short* dl;
            if (c < DD) { dh = a_hi + (size_t)c * MTOT; dl = a_lo + (size_t)c * MTOT; }
            else        { dh = b_hi + (size_t)(c - DD) * MTOT; dl = b_lo + (size_t)(c - DD) * MTOT; }
            *(ushort4*)(dh + r0 + ty * 4) = h4;
            *(ushort4*)(dl + r0 + ty * 4) = l4;
        }
    }
}

// ---------------------------------------------------------------------------
// Stage 2: t_t[d] = A_d * B_d^T via split-bf16 MFMA.
// 2048 blocks x 256 threads; block = 128x128 tile of one d-plane.
// 4 waves, each computes a 64x64 quadrant and stages one 8KB LDS tile.
// ---------------------------------------------------------------------------
__global__ __launch_bounds__(256, 2) void tm_einsum_mfma(
    const unsigned short* __restrict__ a_hi, const unsigned short* __restrict__ a_lo,
    const unsigned short* __restrict__ b_hi, const unsigned short* __restrict__ b_lo,
    float* __restrict__ t_t)
{
    // 4 tiles of [128 rows][32 k] bf16 = 8KB each: Ah, Al, Bh, Bl
    __shared__ unsigned short smem[4 * 128 * 32];

    const int tid  = threadIdx.x;
    const int wid  = tid >> 6;
    const int lane = tid & 63;

    // block -> (plane p, 128x128 tile), XCD-affine: all 16 tiles of a plane
    // land on the same XCD (assuming round-robin dispatch) so its 2MB A/B
    // panels stay L2-resident.
    const int bid  = blockIdx.x;
    const int xcd  = bid & 7;
    const int idx  = bid >> 3;           // 0..255
    const int p    = xcd + ((idx >> 4) << 3);   // 0..127
    const int tile = idx & 15;
    const int i0   = (tile >> 2) * 128;
    const int j0   = (tile & 3) * 128;

    // staging role: wave 0->Ah, 1->Al, 2->Bh, 3->Bl
    const unsigned short* sp;
    int rb;
    if      (wid == 0) { sp = a_hi; rb = i0; }
    else if (wid == 1) { sp = a_lo; rb = i0; }
    else if (wid == 2) { sp = b_hi; rb = j0; }
    else               { sp = b_lo; rb = j0; }
    sp += (size_t)p * MTOT + (size_t)rb * NROW;
    unsigned short* ltile = smem + wid * 4096;

    const int srow = lane >> 2;          // 0..15 within a 16-row issue
    const int scol = (lane & 3) * 8;     // k-element offset of this 16B chunk

    // fragment element offsets (ushort units) into the LDS tiles
    const int r16 = lane & 15;
    const int kh  = lane >> 4;           // 0..3 -> k-offset kh*8
    const int wr  = wid >> 1, wc = wid & 1;
    int aoff[4], boff[4];
#pragma unroll
    for (int m = 0; m < 4; ++m) aoff[m] = (wr * 64 + m * 16 + r16) * 32 + kh * 8;
#pragma unroll
    for (int n = 0; n < 4; ++n) boff[n] = (wc * 64 + n * 16 + r16) * 32 + kh * 8;

    f32x4 acc[4][4];
#pragma unroll
    for (int m = 0; m < 4; ++m)
#pragma unroll
        for (int n = 0; n < 4; ++n) acc[m][n] = (f32x4){0.f, 0.f, 0.f, 0.f};

    for (int kc = 0; kc < 16; ++kc) {
        const int k0 = kc * 32;
        __syncthreads();                 // previous K-step readers done
        // stage this wave's 8KB tile: 8 issues x (64 lanes x 16B)
        const unsigned short* gk = sp + k0 + scol;
#pragma unroll
        for (int s = 0; s < 8; ++s) {
            const unsigned short* g = gk + (size_t)(s * 16 + srow) * NROW;
            gl_lds16(g, ltile + s * 512);
        }
        __syncthreads();                 // drains vmcnt -> LDS visible

        bf16x8 ah[4], al[4], bh[4], bl[4];
#pragma unroll
        for (int m = 0; m < 4; ++m) {
            ah[m] = *(const bf16x8*)(smem +        aoff[m]);
            al[m] = *(const bf16x8*)(smem + 4096 + aoff[m]);
        }
#pragma unroll
        for (int n = 0; n < 4; ++n) {
            bh[n] = *(const bf16x8*)(smem + 8192  + boff[n]);
            bl[n] = *(const bf16x8*)(smem + 12288 + boff[n]);
        }
#pragma unroll
        for (int m = 0; m < 4; ++m)
#pragma unroll
            for (int n = 0; n < 4; ++n) {
                acc[m][n] = __builtin_amdgcn_mfma_f32_16x16x32_bf16(ah[m], bh[n], acc[m][n], 0, 0, 0);
                acc[m][n] = __builtin_amdgcn_mfma_f32_16x16x32_bf16(ah[m], bl[n], acc[m][n], 0, 0, 0);
                acc[m][n] = __builtin_amdgcn_mfma_f32_16x16x32_bf16(al[m], bh[n], acc[m][n], 0, 0, 0);
            }
    }

    // epilogue: C/D layout (16x16): col = lane&15, row = (lane>>4)*4 + reg
    float* plane = t_t + (size_t)p * MTOT;
    const int rbase = i0 + wr * 64 + kh * 4;
    const int cbase = j0 + wc * 64 + r16;
#pragma unroll
    for (int m = 0; m < 4; ++m)
#pragma unroll
        for (int n = 0; n < 4; ++n) {
            float* dst = plane + (size_t)(rbase + m * 16) * NROW + cbase + n * 16;
#pragma unroll
            for (int r = 0; r < 4; ++r)
                dst[(size_t)r * NROW] = acc[m][n][r];
        }
}

// ---------------------------------------------------------------------------
// Stage 3: recompute go = sigmoid(LN(x) @ g_out^T) in registers, then
// LN(t) @ p_out^T * go -> out.  grid 4096 x 256, 64 rows/block.
// ---------------------------------------------------------------------------
__global__ __launch_bounds__(256, 2) void tm_stage3(
    const float* __restrict__ x,
    const float* __restrict__ nin_w, const float* __restrict__ nin_b,
    const float* __restrict__ g_out_w,
    const float* __restrict__ t_t,
    const float* __restrict__ non_w, const float* __restrict__ non_b,
    const float* __restrict__ p_out_w,
    float* __restrict__ out)
{
    __shared__ float Ts[64][129];   // r-major tile (xn first, then t), +1 pad
    __shared__ float Ws[128][64];   // weight chunk, k-major
    __shared__ float w_s[128], b_s[128];

    const int tid = threadIdx.x;
    const int row = tid >> 2;
    const int q   = tid & 3;
    const int tx  = tid & 15;
    const int ty  = tid >> 4;
    const int r0  = blockIdx.x * 64;

    if (tid < 128) { w_s[tid] = nin_w[tid]; b_s[tid] = nin_b[tid]; }

    // ---- Phase A': LN(x rows) -> Ts[row][k]
    {
        const float* src = x + (size_t)(r0 + row) * DD + q * 32;
        float v[32];
        float s = 0.f, ss = 0.f;
#pragma unroll
        for (int it = 0; it < 8; ++it) {
            float4 f = *(const float4*)(src + it * 4);
            v[it*4+0] = f.x; v[it*4+1] = f.y; v[it*4+2] = f.z; v[it*4+3] = f.w;
            s  += f.x + f.y + f.z + f.w;
            ss += f.x*f.x + f.y*f.y + f.z*f.z + f.w*f.w;
        }
        s  += __shfl_xor(s, 1);  s  += __shfl_xor(s, 2);
        ss += __shfl_xor(ss, 1); ss += __shfl_xor(ss, 2);
        float mu   = s * (1.0f / 128.0f);
        float var  = ss * (1.0f / 128.0f) - mu * mu;
        float rstd = rsqrtf(var + 1e-5f);
        __syncthreads();
#pragma unroll
        for (int j = 0; j < 32; ++j) {
            int jj = (j + q * 8) & 31;          // bank stagger
            int k  = q * 32 + jj;
            Ts[row][k] = (v[jj] - mu) * rstd * w_s[k] + b_s[k];
        }
    }

    // ---- go = sigmoid(xn @ g_out^T), kept in registers (matching tile map)
    float gov[2][4][4];
    for (int cp = 0; cp < 2; ++cp) {
        __syncthreads();
        {
            const float* srcw = g_out_w + (size_t)(cp * 64 + row) * DD + q * 32;
#pragma unroll
            for (int it = 0; it < 8; ++it) {
                float4 f = *(const float4*)(srcw + it * 4);
                int k = q * 32 + it * 4;
                Ws[k+0][row] = f.x; Ws[k+1][row] = f.y;
                Ws[k+2][row] = f.z; Ws[k+3][row] = f.w;
            }
        }
        __syncthreads();
        float acc[4][4] = {};
#pragma unroll 4
        for (int k = 0; k < 128; ++k) {
            float4 w4 = *(const float4*)&Ws[k][tx * 4];
            float wv[4] = {w4.x, w4.y, w4.z, w4.w};
            float av[4];
#pragma unroll
            for (int ri = 0; ri < 4; ++ri) av[ri] = Ts[ty * 4 + ri][k];
#pragma unroll
            for (int ri = 0; ri < 4; ++ri)
#pragma unroll
                for (int ci = 0; ci < 4; ++ci)
                    acc[ri][ci] = fmaf(av[ri], wv[ci], acc[ri][ci]);
        }
#pragma unroll
        for (int ri = 0; ri < 4; ++ri)
#pragma unroll
            for (int ci = 0; ci < 4; ++ci)
                gov[cp][ri][ci] = sigm(acc[ri][ci]);
    }

    // ---- Phase B: load t tile (d-major planes -> r-major LDS), LayerNorm
    __syncthreads();                       // xn readers done
    if (tid < 128) { w_s[tid] = non_w[tid]; b_s[tid] = non_b[tid]; }
    {
        const int rl = tid & 63;
        const int dg = tid >> 6;
        for (int it = 0; it < 32; ++it) {
            int dcur = it * 4 + dg;
            Ts[rl][dcur] = t_t[(size_t)dcur * MTOT + r0 + rl];
        }
    }
    __syncthreads();
    {
        float v2[32];
        float s = 0.f, ss = 0.f;
#pragma unroll
        for (int j = 0; j < 32; ++j) {
            int jj = (j + q * 8) & 31;
            float val = Ts[row][q * 32 + jj];
            v2[j] = val;
            s += val; ss += val * val;
        }
        s  += __shfl_xor(s, 1);  s  += __shfl_xor(s, 2);
        ss += __shfl_xor(ss, 1); ss += __shfl_xor(ss, 2);
        float mu   = s * (1.0f / 128.0f);
        float var  = ss * (1.0f / 128.0f) - mu * mu;
        float rstd = rsqrtf(var + 1e-5f);
#pragma unroll
        for (int j = 0; j < 32; ++j) {
            int jj = (j + q * 8) & 31;
            int k  = q * 32 + jj;
            Ts[row][k] = (v2[j] - mu) * rstd * w_s[k] + b_s[k];
        }
    }

    // ---- Phase C: out = (t_norm @ p_out^T) * go
    for (int cp = 0; cp < 2; ++cp) {
        __syncthreads();
        {
            const float* srcw = p_out_w + (size_t)(cp * 64 + row) * DD + q * 32;
#pragma unroll
            for (int it = 0; it < 8; ++it) {
                float4 f = *(const float4*)(srcw + it * 4);
                int k = q * 32 + it * 4;
                Ws[k+0][row] = f.x; Ws[k+1][row] = f.y;
                Ws[k+2][row] = f.z; Ws[k+3][row] = f.w;
            }
        }
        __syncthreads();
        float acc[4][4] = {};
#pragma unroll 4
        for (int k = 0; k < 128; ++k) {
            float4 w4 = *(const float4*)&Ws[k][tx * 4];
            float wv[4] = {w4.x, w4.y, w4.z, w4.w};
            float av[4];
#pragma unroll
            for (int ri = 0; ri < 4; ++ri) av[ri] = Ts[ty * 4 + ri][k];
#pragma unroll
            for (int ri = 0; ri < 4; ++ri)
#pragma unroll
                for (int ci = 0; ci < 4; ++ci)
                    acc[ri][ci] = fmaf(av[ri], wv[ci], acc[ri][ci]);
        }
#pragma unroll
        for (int ri = 0; ri < 4; ++ri) {
            size_t r = (size_t)(r0 + ty * 4 + ri);
            float4 o;
            o.x = acc[ri][0] * gov[cp][ri][0];
            o.y = acc[ri][1] * gov[cp][ri][1];
            o.z = acc[ri][2] * gov[cp][ri][2];
            o.w = acc[ri][3] * gov[cp][ri][3];
            *(float4*)(out + r * DD + cp * 64 + tx * 4) = o;
        }
    }
}

// ---------------------------------------------------------------------------
extern "C" void kernel_launch(void* const* d_in, const int* in_sizes, int n_in,
                              void* d_out, int out_size, void* d_ws, size_t ws_size,
                              hipStream_t stream)
{
    const float* x       = (const float*)d_in[0];
    const float* nin_w   = (const float*)d_in[1];
    const float* nin_b   = (const float*)d_in[2];
    const float* p_in_w  = (const float*)d_in[3];
    const float* g_in_w  = (const float*)d_in[4];
    const float* non_w   = (const float*)d_in[5];
    const float* non_b   = (const float*)d_in[6];
    const float* p_out_w = (const float*)d_in[7];
    const float* g_out_w = (const float*)d_in[8];
    float* out = (float*)d_out;

    unsigned short* a_hi = (unsigned short*)d_ws;        // [128][262144] bf16
    unsigned short* a_lo = a_hi + (size_t)DD * MTOT;
    unsigned short* b_hi = a_lo + (size_t)DD * MTOT;
    unsigned short* b_lo = b_hi + (size_t)DD * MTOT;
    float*          t_t  = (float*)(b_lo + (size_t)DD * MTOT);  // [128][262144]

    tm_stage1<<<dim3(4096), dim3(256), 0, stream>>>(
        x, nin_w, nin_b, p_in_w, g_in_w, a_hi, a_lo, b_hi, b_lo);
    tm_einsum_mfma<<<dim3(2048), dim3(256), 0, stream>>>(
        a_hi, a_lo, b_hi, b_lo, t_t);
    tm_stage3<<<dim3(4096), dim3(256), 0, stream>>>(
        x, nin_w, nin_b, g_out_w, t_t, non_w, non_b, p_out_w, out);
}

// Round 5
// 835.072 us; speedup vs baseline: 1.7721x; 1.3973x over previous
//
#include <hip/hip_runtime.h>

// TriangleMultiplication (outgoing, ENDING=false), B=1, N=512, D=128, fp32.
//   x_norm = LN(x); h = (x_norm @ p_in^T) * sigmoid(x_norm @ g_in^T)
//   a = h[:,:128] ; b = h[:,128:]
//   t[i,j,d] = sum_k a[i,k,d]*b[j,k,d]
//   out = LN(t) @ p_out^T * sigmoid(x_norm @ g_out^T)
//
// ws layout: a_hi/a_lo/b_hi/b_lo bf16 planes [128][262144] (split-bf16)
//            + t_t fp32 [128][262144]  -> 384 MiB total.
// Wf (fragment-ordered bf16 hi/lo of p_in|g_in, 256 KB) lives in the TAIL of
// the t_t region: wprep writes it, stage1 reads it, then the einsum overwrites
// that region with real t values (stream-ordered, so no extra ws needed).
// Stage1 + einsum both run split-bf16 MFMA (hi*hi + hi*lo + lo*hi).

#define NROW 512
#define MTOT (512 * 512)
#define DD 128

typedef __bf16 bf16x8 __attribute__((ext_vector_type(8)));
typedef float f32x4 __attribute__((ext_vector_type(4)));

__device__ __forceinline__ float sigm(float v) {
    return 1.0f / (1.0f + __expf(-v));
}

// fp32 -> bf16 (RNE) via bit ops
__device__ __forceinline__ unsigned short f2bf(float f) {
    unsigned int u = __float_as_uint(f);
    unsigned int r = (u + 0x7fffu + ((u >> 16) & 1u)) >> 16;
    return (unsigned short)r;
}
__device__ __forceinline__ float bf2f(unsigned short h) {
    return __uint_as_float(((unsigned int)h) << 16);
}

__device__ __forceinline__ void gl_lds16(const void* g, void* l) {
    __builtin_amdgcn_global_load_lds(
        (const __attribute__((address_space(1))) void*)g,
        (__attribute__((address_space(3))) void*)l, 16, 0, 0);
}

// ---------------------------------------------------------------------------
// W-prep: p_in|g_in (512 x 128 fp32) -> fragment-ordered bf16 hi/lo.
// Frag layout: for n-tile nt (16 cols), k-step ks (32 k): 1KB hi + 1KB lo,
// lane l = (col&15) + 16*kh holds W[col][ks*32 + kh*8 .. +7].
// ---------------------------------------------------------------------------
__global__ void tm_wprep(const float* __restrict__ p_in_w,
                         const float* __restrict__ g_in_w,
                         unsigned short* __restrict__ wf)
{
    const int c = blockIdx.x;      // 0..511 (proj 0..255, gate 256..511)
    const int k = threadIdx.x;     // 0..127
    float wv = (c < 256) ? p_in_w[c * 128 + k] : g_in_w[(c - 256) * 128 + k];
    unsigned short hi = f2bf(wv);
    unsigned short lo = f2bf(wv - bf2f(hi));
    const int nt = c >> 4, r16 = c & 15;
    const int ks = k >> 5, kh = (k >> 3) & 3, e = k & 7;
    const int lane = r16 + (kh << 4);
    const size_t base = (size_t)(nt * 4 + ks) * 1024 + lane * 8 + e;
    wf[base] = hi;          // hi half of the 2KB frag-block
    wf[base + 512] = lo;    // lo half
}

// ---------------------------------------------------------------------------
// Stage 1 (MFMA): LN(x) -> split-bf16 A-tile in LDS (XOR-swizzled) ->
// dual GEMM vs frag-ordered W from global (L2) -> h = p*sig(g) -> planes.
// grid (2048 row-groups, 2 col-halves) x 256 threads (4 waves).
// Wave w: 128 rows x 32 h-cols (2 proj + 2 gate n-tiles), 8 m-tiles.
// ---------------------------------------------------------------------------
__global__ __launch_bounds__(256, 2) void tm_stage1_mfma(
    const float* __restrict__ x,
    const float* __restrict__ nin_w, const float* __restrict__ nin_b,
    const unsigned short* __restrict__ wf,
    unsigned short* __restrict__ a_hi, unsigned short* __restrict__ a_lo,
    unsigned short* __restrict__ b_hi, unsigned short* __restrict__ b_lo)
{
    __shared__ char Asm[65536];        // hi tile [128][128] bf16, lo at +32768
    __shared__ float wln[128], bln[128];

    const int tid  = threadIdx.x;
    const int wid  = tid >> 6;
    const int lane = tid & 63;
    const int r0   = blockIdx.x * 128;
    const int hc0  = blockIdx.y * 128;   // 0 -> a planes, 128 -> b planes

    if (tid < 128) { wln[tid] = nin_w[tid]; bln[tid] = nin_b[tid]; }

    // ---- LN phase: 2 threads/row, 64 elems each
    {
        const int row = tid >> 1;
        const int hf  = tid & 1;
        const float* src = x + (size_t)(r0 + row) * DD + hf * 64;
        float v[64];
        float s = 0.f, ss = 0.f;
#pragma unroll
        for (int it = 0; it < 16; ++it) {
            float4 f = *(const float4*)(src + it * 4);
            v[it*4+0] = f.x; v[it*4+1] = f.y; v[it*4+2] = f.z; v[it*4+3] = f.w;
            s  += f.x + f.y + f.z + f.w;
            ss += f.x*f.x + f.y*f.y + f.z*f.z + f.w*f.w;
        }
        s  += __shfl_xor(s, 1);
        ss += __shfl_xor(ss, 1);
        float mu   = s * (1.0f / 128.0f);
        float var  = ss * (1.0f / 128.0f) - mu * mu;
        float rstd = rsqrtf(var + 1e-5f);
        __syncthreads();               // wln/bln ready
#pragma unroll
        for (int j = 0; j < 8; ++j) {
            const int k0 = hf * 64 + j * 8;
            unsigned short h8[8], l8[8];
#pragma unroll
            for (int e = 0; e < 8; ++e) {
                float xn = (v[j*8+e] - mu) * rstd * wln[k0+e] + bln[k0+e];
                unsigned short h = f2bf(xn);
                h8[e] = h; l8[e] = f2bf(xn - bf2f(h));
            }
            int byte = row * 256 + k0 * 2;
            byte ^= (row & 7) << 4;    // bank swizzle
            *(bf16x8*)(Asm + byte)         = *(bf16x8*)h8;
            *(bf16x8*)(Asm + 32768 + byte) = *(bf16x8*)l8;
        }
    }
    __syncthreads();                   // A-tiles visible to all waves

    // ---- GEMM phase
    const int r16 = lane & 15;
    const int kh  = lane >> 4;         // 0..3
    const int ntp0 = (hc0 >> 4) + wid * 2;        // proj n-tile (global frag id)
    const int ntg0 = 16 + (hc0 >> 4) + wid * 2;   // gate n-tile

    f32x4 accP[8][2], accG[8][2];
#pragma unroll
    for (int m = 0; m < 8; ++m)
#pragma unroll
        for (int t = 0; t < 2; ++t) {
            accP[m][t] = (f32x4){0.f,0.f,0.f,0.f};
            accG[m][t] = (f32x4){0.f,0.f,0.f,0.f};
        }

#pragma unroll
    for (int ks = 0; ks < 4; ++ks) {
        bf16x8 ah[8], al[8];
#pragma unroll
        for (int m = 0; m < 8; ++m) {
            const int row = m * 16 + r16;
            int byte = row * 256 + ks * 64 + kh * 16;
            byte ^= (row & 7) << 4;
            ah[m] = *(const bf16x8*)(Asm + byte);
            al[m] = *(const bf16x8*)(Asm + 32768 + byte);
        }
#pragma unroll
        for (int tc = 0; tc < 2; ++tc) {
            {   // proj
                const unsigned short* fp =
                    wf + (size_t)((ntp0 + tc) * 4 + ks) * 1024 + lane * 8;
                bf16x8 bh = *(const bf16x8*)fp;
                bf16x8 bl = *(const bf16x8*)(fp + 512);
#pragma unroll
                for (int m = 0; m < 8; ++m) {
                    accP[m][tc] = __builtin_amdgcn_mfma_f32_16x16x32_bf16(ah[m], bh, accP[m][tc], 0, 0, 0);
                    accP[m][tc] = __builtin_amdgcn_mfma_f32_16x16x32_bf16(ah[m], bl, accP[m][tc], 0, 0, 0);
                    accP[m][tc] = __builtin_amdgcn_mfma_f32_16x16x32_bf16(al[m], bh, accP[m][tc], 0, 0, 0);
                }
            }
            {   // gate
                const unsigned short* fp =
                    wf + (size_t)((ntg0 + tc) * 4 + ks) * 1024 + lane * 8;
                bf16x8 bh = *(const bf16x8*)fp;
                bf16x8 bl = *(const bf16x8*)(fp + 512);
#pragma unroll
                for (int m = 0; m < 8; ++m) {
                    accG[m][tc] = __builtin_amdgcn_mfma_f32_16x16x32_bf16(ah[m], bh, accG[m][tc], 0, 0, 0);
                    accG[m][tc] = __builtin_amdgcn_mfma_f32_16x16x32_bf16(ah[m], bl, accG[m][tc], 0, 0, 0);
                    accG[m][tc] = __builtin_amdgcn_mfma_f32_16x16x32_bf16(al[m], bh, accG[m][tc], 0, 0, 0);
                }
            }
        }
    }

    // ---- epilogue: h = p * sigm(g); split hi/lo; store to d-major planes.
    // C/D: col = r16 (within 16-tile), row = kh*4 + reg.
    unsigned short* ph = hc0 ? b_hi : a_hi;
    unsigned short* pl = hc0 ? b_lo : a_lo;
#pragma unroll
    for (int tc = 0; tc < 2; ++tc) {
        const int d = (wid * 2 + tc) * 16 + r16;   // 0..127 within plane set
        unsigned short* dh = ph + (size_t)d * MTOT;
        unsigned short* dl = pl + (size_t)d * MTOT;
#pragma unroll
        for (int m = 0; m < 8; ++m) {
            const int grow0 = r0 + m * 16 + kh * 4;
            ushort4 h4, l4;
#pragma unroll
            for (int reg = 0; reg < 4; ++reg) {
                float hv = accP[m][tc][reg] * sigm(accG[m][tc][reg]);
                unsigned short h = f2bf(hv);
                unsigned short l = f2bf(hv - bf2f(h));
                if (reg == 0) { h4.x = h; l4.x = l; }
                if (reg == 1) { h4.y = h; l4.y = l; }
                if (reg == 2) { h4.z = h; l4.z = l; }
                if (reg == 3) { h4.w = h; l4.w = l; }
            }
            *(ushort4*)(dh + grow0) = h4;
            *(ushort4*)(dl + grow0) = l4;
        }
    }
}

// ---------------------------------------------------------------------------
// Stage 2: t_t[d] = A_d * B_d^T via split-bf16 MFMA. (unchanged, validated)
// ---------------------------------------------------------------------------
__global__ __launch_bounds__(256, 2) void tm_einsum_mfma(
    const unsigned short* __restrict__ a_hi, const unsigned short* __restrict__ a_lo,
    const unsigned short* __restrict__ b_hi, const unsigned short* __restrict__ b_lo,
    float* __restrict__ t_t)
{
    __shared__ unsigned short smem[4 * 128 * 32];

    const int tid  = threadIdx.x;
    const int wid  = tid >> 6;
    const int lane = tid & 63;

    const int bid  = blockIdx.x;
    const int xcd  = bid & 7;
    const int idx  = bid >> 3;
    const int p    = xcd + ((idx >> 4) << 3);
    const int tile = idx & 15;
    const int i0   = (tile >> 2) * 128;
    const int j0   = (tile & 3) * 128;

    const unsigned short* sp;
    int rb;
    if      (wid == 0) { sp = a_hi; rb = i0; }
    else if (wid == 1) { sp = a_lo; rb = i0; }
    else if (wid == 2) { sp = b_hi; rb = j0; }
    else               { sp = b_lo; rb = j0; }
    sp += (size_t)p * MTOT + (size_t)rb * NROW;
    unsigned short* ltile = smem + wid * 4096;

    const int srow = lane >> 2;
    const int scol = (lane & 3) * 8;

    const int r16 = lane & 15;
    const int kh  = lane >> 4;
    const int wr  = wid >> 1, wc = wid & 1;
    int aoff[4], boff[4];
#pragma unroll
    for (int m = 0; m < 4; ++m) aoff[m] = (wr * 64 + m * 16 + r16) * 32 + kh * 8;
#pragma unroll
    for (int n = 0; n < 4; ++n) boff[n] = (wc * 64 + n * 16 + r16) * 32 + kh * 8;

    f32x4 acc[4][4];
#pragma unroll
    for (int m = 0; m < 4; ++m)
#pragma unroll
        for (int n = 0; n < 4; ++n) acc[m][n] = (f32x4){0.f, 0.f, 0.f, 0.f};

    for (int kc = 0; kc < 16; ++kc) {
        const int k0 = kc * 32;
        __syncthreads();
        const unsigned short* gk = sp + k0 + scol;
#pragma unroll
        for (int s = 0; s < 8; ++s) {
            const unsigned short* g = gk + (size_t)(s * 16 + srow) * NROW;
            gl_lds16(g, ltile + s * 512);
        }
        __syncthreads();

        bf16x8 ah[4], al[4], bh[4], bl[4];
#pragma unroll
        for (int m = 0; m < 4; ++m) {
            ah[m] = *(const bf16x8*)(smem +        aoff[m]);
            al[m] = *(const bf16x8*)(smem + 4096 + aoff[m]);
        }
#pragma unroll
        for (int n = 0; n < 4; ++n) {
            bh[n] = *(const bf16x8*)(smem + 8192  + boff[n]);
            bl[n] = *(const bf16x8*)(smem + 12288 + boff[n]);
        }
#pragma unroll
        for (int m = 0; m < 4; ++m)
#pragma unroll
            for (int n = 0; n < 4; ++n) {
                acc[m][n] = __builtin_amdgcn_mfma_f32_16x16x32_bf16(ah[m], bh[n], acc[m][n], 0, 0, 0);
                acc[m][n] = __builtin_amdgcn_mfma_f32_16x16x32_bf16(ah[m], bl[n], acc[m][n], 0, 0, 0);
                acc[m][n] = __builtin_amdgcn_mfma_f32_16x16x32_bf16(al[m], bh[n], acc[m][n], 0, 0, 0);
            }
    }

    float* plane = t_t + (size_t)p * MTOT;
    const int rbase = i0 + wr * 64 + kh * 4;
    const int cbase = j0 + wc * 64 + r16;
#pragma unroll
    for (int m = 0; m < 4; ++m)
#pragma unroll
        for (int n = 0; n < 4; ++n) {
            float* dst = plane + (size_t)(rbase + m * 16) * NROW + cbase + n * 16;
#pragma unroll
            for (int r = 0; r < 4; ++r)
                dst[(size_t)r * NROW] = acc[m][n][r];
        }
}

// ---------------------------------------------------------------------------
// Stage 3: recompute go = sigmoid(LN(x) @ g_out^T), then LN(t) @ p_out^T * go.
// (unchanged, validated)
// ---------------------------------------------------------------------------
__global__ __launch_bounds__(256, 2) void tm_stage3(
    const float* __restrict__ x,
    const float* __restrict__ nin_w, const float* __restrict__ nin_b,
    const float* __restrict__ g_out_w,
    const float* __restrict__ t_t,
    const float* __restrict__ non_w, const float* __restrict__ non_b,
    const float* __restrict__ p_out_w,
    float* __restrict__ out)
{
    __shared__ float Ts[64][129];
    __shared__ float Ws[128][64];
    __shared__ float w_s[128], b_s[128];

    const int tid = threadIdx.x;
    const int row = tid >> 2;
    const int q   = tid & 3;
    const int tx  = tid & 15;
    const int ty  = tid >> 4;
    const int r0  = blockIdx.x * 64;

    if (tid < 128) { w_s[tid] = nin_w[tid]; b_s[tid] = nin_b[tid]; }

    {
        const float* src = x + (size_t)(r0 + row) * DD + q * 32;
        float v[32];
        float s = 0.f, ss = 0.f;
#pragma unroll
        for (int it = 0; it < 8; ++it) {
            float4 f = *(const float4*)(src + it * 4);
            v[it*4+0] = f.x; v[it*4+1] = f.y; v[it*4+2] = f.z; v[it*4+3] = f.w;
            s  += f.x + f.y + f.z + f.w;
            ss += f.x*f.x + f.y*f.y + f.z*f.z + f.w*f.w;
        }
        s  += __shfl_xor(s, 1);  s  += __shfl_xor(s, 2);
        ss += __shfl_xor(ss, 1); ss += __shfl_xor(ss, 2);
        float mu   = s * (1.0f / 128.0f);
        float var  = ss * (1.0f / 128.0f) - mu * mu;
        float rstd = rsqrtf(var + 1e-5f);
        __syncthreads();
#pragma unroll
        for (int j = 0; j < 32; ++j) {
            int jj = (j + q * 8) & 31;
            int k  = q * 32 + jj;
            Ts[row][k] = (v[jj] - mu) * rstd * w_s[k] + b_s[k];
        }
    }

    float gov[2][4][4];
    for (int cp = 0; cp < 2; ++cp) {
        __syncthreads();
        {
            const float* srcw = g_out_w + (size_t)(cp * 64 + row) * DD + q * 32;
#pragma unroll
            for (int it = 0; it < 8; ++it) {
                float4 f = *(const float4*)(srcw + it * 4);
                int k = q * 32 + it * 4;
                Ws[k+0][row] = f.x; Ws[k+1][row] = f.y;
                Ws[k+2][row] = f.z; Ws[k+3][row] = f.w;
            }
        }
        __syncthreads();
        float acc[4][4] = {};
#pragma unroll 4
        for (int k = 0; k < 128; ++k) {
            float4 w4 = *(const float4*)&Ws[k][tx * 4];
            float wv[4] = {w4.x, w4.y, w4.z, w4.w};
            float av[4];
#pragma unroll
            for (int ri = 0; ri < 4; ++ri) av[ri] = Ts[ty * 4 + ri][k];
#pragma unroll
            for (int ri = 0; ri < 4; ++ri)
#pragma unroll
                for (int ci = 0; ci < 4; ++ci)
                    acc[ri][ci] = fmaf(av[ri], wv[ci], acc[ri][ci]);
        }
#pragma unroll
        for (int ri = 0; ri < 4; ++ri)
#pragma unroll
            for (int ci = 0; ci < 4; ++ci)
                gov[cp][ri][ci] = sigm(acc[ri][ci]);
    }

    __syncthreads();
    if (tid < 128) { w_s[tid] = non_w[tid]; b_s[tid] = non_b[tid]; }
    {
        const int rl = tid & 63;
        const int dg = tid >> 6;
        for (int it = 0; it < 32; ++it) {
            int dcur = it * 4 + dg;
            Ts[rl][dcur] = t_t[(size_t)dcur * MTOT + r0 + rl];
        }
    }
    __syncthreads();
    {
        float v2[32];
        float s = 0.f, ss = 0.f;
#pragma unroll
        for (int j = 0; j < 32; ++j) {
            int jj = (j + q * 8) & 31;
            float val = Ts[row][q * 32 + jj];
            v2[j] = val;
            s += val; ss += val * val;
        }
        s  += __shfl_xor(s, 1);  s  += __shfl_xor(s, 2);
        ss += __shfl_xor(ss, 1); ss += __shfl_xor(ss, 2);
        float mu   = s * (1.0f / 128.0f);
        float var  = ss * (1.0f / 128.0f) - mu * mu;
        float rstd = rsqrtf(var + 1e-5f);
#pragma unroll
        for (int j = 0; j < 32; ++j) {
            int jj = (j + q * 8) & 31;
            int k  = q * 32 + jj;
            Ts[row][k] = (v2[j] - mu) * rstd * w_s[k] + b_s[k];
        }
    }

    for (int cp = 0; cp < 2; ++cp) {
        __syncthreads();
        {
            const float* srcw = p_out_w + (size_t)(cp * 64 + row) * DD + q * 32;
#pragma unroll
            for (int it = 0; it < 8; ++it) {
                float4 f = *(const float4*)(srcw + it * 4);
                int k = q * 32 + it * 4;
                Ws[k+0][row] = f.x; Ws[k+1][row] = f.y;
                Ws[k+2][row] = f.z; Ws[k+3][row] = f.w;
            }
        }
        __syncthreads();
        float acc[4][4] = {};
#pragma unroll 4
        for (int k = 0; k < 128; ++k) {
            float4 w4 = *(const float4*)&Ws[k][tx * 4];
            float wv[4] = {w4.x, w4.y, w4.z, w4.w};
            float av[4];
#pragma unroll
            for (int ri = 0; ri < 4; ++ri) av[ri] = Ts[ty * 4 + ri][k];
#pragma unroll
            for (int ri = 0; ri < 4; ++ri)
#pragma unroll
                for (int ci = 0; ci < 4; ++ci)
                    acc[ri][ci] = fmaf(av[ri], wv[ci], acc[ri][ci]);
        }
#pragma unroll
        for (int ri = 0; ri < 4; ++ri) {
            size_t r = (size_t)(r0 + ty * 4 + ri);
            float4 o;
            o.x = acc[ri][0] * gov[cp][ri][0];
            o.y = acc[ri][1] * gov[cp][ri][1];
            o.z = acc[ri][2] * gov[cp][ri][2];
            o.w = acc[ri][3] * gov[cp][ri][3];
            *(float4*)(out + r * DD + cp * 64 + tx * 4) = o;
        }
    }
}

// ---------------------------------------------------------------------------
extern "C" void kernel_launch(void* const* d_in, const int* in_sizes, int n_in,
                              void* d_out, int out_size, void* d_ws, size_t ws_size,
                              hipStream_t stream)
{
    const float* x       = (const float*)d_in[0];
    const float* nin_w   = (const float*)d_in[1];
    const float* nin_b   = (const float*)d_in[2];
    const float* p_in_w  = (const float*)d_in[3];
    const float* g_in_w  = (const float*)d_in[4];
    const float* non_w   = (const float*)d_in[5];
    const float* non_b   = (const float*)d_in[6];
    const float* p_out_w = (const float*)d_in[7];
    const float* g_out_w = (const float*)d_in[8];
    float* out = (float*)d_out;

    unsigned short* a_hi = (unsigned short*)d_ws;        // [128][262144] bf16
    unsigned short* a_lo = a_hi + (size_t)DD * MTOT;
    unsigned short* b_hi = a_lo + (size_t)DD * MTOT;
    unsigned short* b_lo = b_hi + (size_t)DD * MTOT;
    float*          t_t  = (float*)(b_lo + (size_t)DD * MTOT);  // [128][262144]
    // Wf: 256 KB carved from the TAIL of t_t (dead until einsum overwrites it)
    unsigned short* wf   = (unsigned short*)(t_t + (size_t)DD * MTOT) - 131072;

    tm_wprep<<<dim3(512), dim3(128), 0, stream>>>(p_in_w, g_in_w, wf);
    tm_stage1_mfma<<<dim3(2048, 2), dim3(256), 0, stream>>>(
        x, nin_w, nin_b, wf, a_hi, a_lo, b_hi, b_lo);
    tm_einsum_mfma<<<dim3(2048), dim3(256), 0, stream>>>(
        a_hi, a_lo, b_hi, b_lo, t_t);
    tm_stage3<<<dim3(4096), dim3(256), 0, stream>>>(
        x, nin_w, nin_b, g_out_w, t_t, non_w, non_b, p_out_w, out);
}